// Round 1
// baseline (786.006 us; speedup 1.0000x reference)
//
#include <hip/hip_runtime.h>
#include <hip/hip_bf16.h>
#include <stdint.h>

// B=8192, D=2048, M=8, C=1000, N = M*C = 8000
#define BDIM 8192
#define DDIM 2048
#define MDIM 8
#define CDIM 1000
#define NDIM 8000

typedef __attribute__((ext_vector_type(8))) short bf16x8;
typedef __attribute__((ext_vector_type(4))) float f32x4;

__device__ __forceinline__ unsigned short f2bf(float f) {
    union { float f; unsigned u; } v; v.f = f;
    unsigned r = v.u + 0x7fffu + ((v.u >> 16) & 1u);   // round-to-nearest-even
    return (unsigned short)(r >> 16);
}

__device__ __forceinline__ void gl_lds16(const void* g, void* l) {
    __builtin_amdgcn_global_load_lds(
        (const __attribute__((address_space(1))) void*)g,
        (__attribute__((address_space(3))) void*)l,
        16, 0, 0);
}

// ---------------- cast x (fp32 -> bf16), vectorized ----------------
__global__ void cast_x_kernel(const float4* __restrict__ x, ushort* __restrict__ xb) {
    int i = blockIdx.x * blockDim.x + threadIdx.x;   // 4 floats per thread
    float4 v = x[i];
    ushort4 o;
    o.x = f2bf(v.x); o.y = f2bf(v.y); o.z = f2bf(v.z); o.w = f2bf(v.w);
    *(ushort4*)&xb[(size_t)i * 4] = o;
}

// ---- transpose+cast model_weights (M,D,C) -> Wb[n][d], n = m*C+c ----
__global__ void transpose_cast_w(const float* __restrict__ MW, ushort* __restrict__ Wb) {
    __shared__ float tile[32][33];
    int m  = blockIdx.z;
    int c0 = blockIdx.x * 32;
    int d0 = blockIdx.y * 32;
    int tx = threadIdx.x, ty = threadIdx.y;
    const float* src = MW + (size_t)m * DDIM * CDIM;
#pragma unroll
    for (int i = 0; i < 4; i++) {
        int d = d0 + ty + i * 8;
        int c = c0 + tx;
        tile[ty + i * 8][tx] = (c < CDIM) ? src[(size_t)d * CDIM + c] : 0.f;
    }
    __syncthreads();
#pragma unroll
    for (int i = 0; i < 4; i++) {
        int c = c0 + ty + i * 8;
        int d = d0 + tx;
        if (c < CDIM)
            Wb[((size_t)(m * CDIM + c)) * DDIM + d] = f2bf(tile[tx][ty + i * 8]);
    }
}

// ---- transpose+cast resnet_weight (D, N) -> Rb[n][d] ----
__global__ void transpose_cast_r(const float* __restrict__ R, ushort* __restrict__ Rb) {
    __shared__ float tile[32][33];
    int n0 = blockIdx.x * 32;
    int d0 = blockIdx.y * 32;
    int tx = threadIdx.x, ty = threadIdx.y;
#pragma unroll
    for (int i = 0; i < 4; i++) {
        int d = d0 + ty + i * 8;
        tile[ty + i * 8][tx] = R[(size_t)d * NDIM + n0 + tx];
    }
    __syncthreads();
#pragma unroll
    for (int i = 0; i < 4; i++) {
        int n = n0 + ty + i * 8;
        int d = d0 + tx;
        Rb[(size_t)n * DDIM + d] = f2bf(tile[tx][ty + i * 8]);
    }
}

// ---------------- fused dual-B GEMM + product epilogue ----------------
// A: xb [8192][2048] bf16 row-major
// B1: Wb [8000][2048] bf16 (B^T layout), B2: Rb [8000][2048]
// out[b][c] += sum over this block's n-tile of (A@B1^T + mb)[b][n] * (A@B2^T + rb)[b][n]
#define BM 128
#define BN 64
#define BK 64

__global__ __launch_bounds__(256, 2) void gemm_fused(
    const ushort* __restrict__ xb, const ushort* __restrict__ wb,
    const ushort* __restrict__ rb,
    const float* __restrict__ mbias, const float* __restrict__ rbias,
    float* __restrict__ out) {
    __shared__ ushort As[BM * BK];   // [row][k] 128x64
    __shared__ ushort B1s[BN * BK];  // [n][k] 64x64
    __shared__ ushort B2s[BN * BK];

    int tid  = threadIdx.x;
    int lane = tid & 63;
    int wid  = tid >> 6;          // 0..3
    int wrow = wid >> 1;          // 0..1 -> 64-row half
    int wcol = wid & 1;           // 0..1 -> 32-col half
    int brow = blockIdx.y * BM;
    int bn0  = blockIdx.x * BN;
    int wbase = tid & ~63;        // wave-uniform chunk base

    f32x4 acc1[4][2] = {};
    f32x4 acc2[4][2] = {};

    for (int kt = 0; kt < DDIM; kt += BK) {
        // stage A: 128 rows x 128B = 1024 x 16B chunks, 4 per thread
#pragma unroll
        for (int it = 0; it < 4; it++) {
            int chunk = it * 256 + tid;
            int r = chunk >> 3, cc = chunk & 7;
            gl_lds16(xb + (size_t)(brow + r) * DDIM + kt + cc * 8,
                     &As[(size_t)(it * 256 + wbase) * 8]);
        }
        // stage B1/B2: 64 rows x 128B = 512 chunks each, 2 per thread
#pragma unroll
        for (int it = 0; it < 2; it++) {
            int chunk = it * 256 + tid;
            int r = chunk >> 3, cc = chunk & 7;
            gl_lds16(wb + (size_t)(bn0 + r) * DDIM + kt + cc * 8,
                     &B1s[(size_t)(it * 256 + wbase) * 8]);
            gl_lds16(rb + (size_t)(bn0 + r) * DDIM + kt + cc * 8,
                     &B2s[(size_t)(it * 256 + wbase) * 8]);
        }
        __syncthreads();

#pragma unroll
        for (int kk = 0; kk < BK; kk += 32) {
            int colo = kk + ((lane >> 4) << 3);
            bf16x8 a[4], b1f[2], b2f[2];
#pragma unroll
            for (int i = 0; i < 4; i++)
                a[i] = *(const bf16x8*)&As[(wrow * 64 + i * 16 + (lane & 15)) * BK + colo];
#pragma unroll
            for (int j = 0; j < 2; j++) {
                b1f[j] = *(const bf16x8*)&B1s[(wcol * 32 + j * 16 + (lane & 15)) * BK + colo];
                b2f[j] = *(const bf16x8*)&B2s[(wcol * 32 + j * 16 + (lane & 15)) * BK + colo];
            }
#pragma unroll
            for (int i = 0; i < 4; i++)
#pragma unroll
                for (int j = 0; j < 2; j++) {
                    acc1[i][j] = __builtin_amdgcn_mfma_f32_16x16x32_bf16(a[i], b1f[j], acc1[i][j], 0, 0, 0);
                    acc2[i][j] = __builtin_amdgcn_mfma_f32_16x16x32_bf16(a[i], b2f[j], acc2[i][j], 0, 0, 0);
                }
        }
        __syncthreads();
    }

    // epilogue: p = (acc1 + mb[n]) * (acc2 + rb[n]); atomicAdd out[b*1000 + n%1000]
#pragma unroll
    for (int j = 0; j < 2; j++) {
        int n = bn0 + wcol * 32 + j * 16 + (lane & 15);
        float bb1 = mbias[n];
        float bb2 = rbias[n];
        int mi = n / CDIM;
        int c  = n - mi * CDIM;
#pragma unroll
        for (int i = 0; i < 4; i++) {
#pragma unroll
            for (int r = 0; r < 4; r++) {
                int b = brow + wrow * 64 + i * 16 + ((lane >> 4) << 2) + r;
                float v = (acc1[i][j][r] + bb1) * (acc2[i][j][r] + bb2);
                atomicAdd(&out[(size_t)b * CDIM + c], v);
            }
        }
    }
}

extern "C" void kernel_launch(void* const* d_in, const int* in_sizes, int n_in,
                              void* d_out, int out_size, void* d_ws, size_t ws_size,
                              hipStream_t stream) {
    const float* x   = (const float*)d_in[0];   // [8192][2048]
    const float* mw  = (const float*)d_in[1];   // [8][2048][1000]
    const float* mb  = (const float*)d_in[2];   // [8][1000] flat = [8000]
    const float* rw  = (const float*)d_in[3];   // [2048][8000]
    const float* rbv = (const float*)d_in[4];   // [8000]
    float* out = (float*)d_out;                 // [8192][1000]

    char* ws = (char*)d_ws;
    ushort* xb = (ushort*)ws;                                   // 33,554,432 B
    ushort* wb = (ushort*)(ws + (size_t)33554432);              // 32,768,000 B
    ushort* rb = (ushort*)(ws + (size_t)33554432 + 32768000);   // 32,768,000 B

    hipMemsetAsync(out, 0, (size_t)out_size * sizeof(float), stream);

    cast_x_kernel<<<BDIM * DDIM / (256 * 4), 256, 0, stream>>>((const float4*)x, xb);
    transpose_cast_w<<<dim3(32, DDIM / 32, MDIM), dim3(32, 8), 0, stream>>>(mw, wb);
    transpose_cast_r<<<dim3(NDIM / 32, DDIM / 32), dim3(32, 8), 0, stream>>>(rw, rb);

    gemm_fused<<<dim3(NDIM / BN, BDIM / BM), 256, 0, stream>>>(xb, wb, rb, mb, rbv, out);
}

// Round 2
// 605.586 us; speedup vs baseline: 1.2979x; 1.2979x over previous
//
#include <hip/hip_runtime.h>
#include <hip/hip_bf16.h>
#include <stdint.h>

// B=8192, D=2048, M=8, C=1000; padded: CPAD=1024, NPAD=8192 (n' = c*8 + m)
#define BDIM 8192
#define DDIM 2048
#define MDIM 8
#define CDIM 1000
#define CPAD 1024
#define NPAD 8192

typedef __attribute__((ext_vector_type(8))) short bf16x8;
typedef __attribute__((ext_vector_type(4))) float f32x4;

__device__ __forceinline__ unsigned short f2bf(float f) {
    union { float f; unsigned u; } v; v.f = f;
    unsigned r = v.u + 0x7fffu + ((v.u >> 16) & 1u);   // RNE
    return (unsigned short)(r >> 16);
}

__device__ __forceinline__ void gl_lds16(const void* g, void* l) {
    __builtin_amdgcn_global_load_lds(
        (const __attribute__((address_space(1))) void*)g,
        (__attribute__((address_space(3))) void*)l,
        16, 0, 0);
}

// ---------------- prep: cast x (fp32 -> bf16) ----------------
__global__ void cast_x_kernel(const float4* __restrict__ x, ushort* __restrict__ xb) {
    int i = blockIdx.x * blockDim.x + threadIdx.x;
    float4 v = x[i];
    ushort4 o;
    o.x = f2bf(v.x); o.y = f2bf(v.y); o.z = f2bf(v.z); o.w = f2bf(v.w);
    *(ushort4*)&xb[(size_t)i * 4] = o;
}

// ---- prep: model_weights (M,D,C) -> wb[n'=c*8+m][d], zero-pad c>=1000 ----
__global__ void prep_w(const float* __restrict__ MW, ushort* __restrict__ wb) {
    __shared__ float tile[32][33];
    int m  = blockIdx.z;
    int c0 = blockIdx.x * 32;
    int d0 = blockIdx.y * 32;
    int tx = threadIdx.x, ty = threadIdx.y;
    const float* src = MW + (size_t)m * DDIM * CDIM;
#pragma unroll
    for (int i = 0; i < 4; i++) {
        int d = d0 + ty + i * 8;
        int c = c0 + tx;
        tile[ty + i * 8][tx] = (c < CDIM) ? src[(size_t)d * CDIM + c] : 0.f;
    }
    __syncthreads();
#pragma unroll
    for (int i = 0; i < 4; i++) {
        int c = c0 + ty + i * 8;
        int d = d0 + tx;
        wb[(size_t)(c * 8 + m) * DDIM + d] = f2bf(tile[tx][ty + i * 8]);
    }
}

// ---- prep: resnet_weight (D, 8000) -> rb[n'=c*8+m][d], zero-pad c>=1000 ----
__global__ void prep_r(const float* __restrict__ R, ushort* __restrict__ rb) {
    __shared__ float tile[32][33];
    int m  = blockIdx.z;
    int c0 = blockIdx.x * 32;
    int d0 = blockIdx.y * 32;
    int tx = threadIdx.x, ty = threadIdx.y;
#pragma unroll
    for (int i = 0; i < 4; i++) {
        int d = d0 + ty + i * 8;
        int c = c0 + tx;
        tile[ty + i * 8][tx] = (c < CDIM) ? R[(size_t)d * (MDIM * CDIM) + m * CDIM + c] : 0.f;
    }
    __syncthreads();
#pragma unroll
    for (int i = 0; i < 4; i++) {
        int c = c0 + ty + i * 8;
        int d = d0 + tx;
        rb[(size_t)(c * 8 + m) * DDIM + d] = f2bf(tile[tx][ty + i * 8]);
    }
}

// ---- prep: biases -> interleaved padded float arrays [NPAD] ----
__global__ void prep_bias(const float* __restrict__ mb, const float* __restrict__ rbv,
                          float* __restrict__ mb2, float* __restrict__ rb2) {
    int n = blockIdx.x * 256 + threadIdx.x;   // 0..8191
    int c = n >> 3, m = n & 7;
    mb2[n] = (c < CDIM) ? mb[m * CDIM + c] : 0.f;
    rb2[n] = (c < CDIM) ? rbv[m * CDIM + c] : 0.f;
}

// ---------------- fused dual-B GEMM, 4-phase pipelined ----------------
#define BM 256
#define BN 128
#define BK 64
#define NT (DDIM / BK)   // 32

// stage one 16KB unit (128 rows x 64 ushorts), inverse-swizzled global source,
// linear LDS dest (wave-uniform base + lane*16)
#define STAGE(G, L) do {                                                       \
    _Pragma("unroll")                                                          \
    for (int it_ = 0; it_ < 2; ++it_) {                                        \
        int ci_ = it_ * 512 + tid;                                             \
        int r_ = ci_ >> 3, cc_ = ci_ & 7;                                      \
        gl_lds16((G) + (size_t)r_ * DDIM + (size_t)((cc_ ^ (r_ & 7)) << 3),    \
                 (L) + (size_t)(it_ * 512 + wbase) * 8);                       \
    }                                                                          \
} while (0)

#define LDA(AC, H) do {                                                        \
    _Pragma("unroll")                                                          \
    for (int i_ = 0; i_ < 4; i_++)                                             \
    _Pragma("unroll")                                                          \
    for (int kh_ = 0; kh_ < 2; kh_++) {                                        \
        int row_ = wm * 128 + (H) * 64 + i_ * 16 + (lane & 15);                \
        int cc_ = kh_ * 4 + (lane >> 4);                                       \
        af[i_][kh_] = *(const bf16x8*)&(AC)[row_ * BK + ((cc_ ^ (row_ & 7)) << 3)]; \
    }                                                                          \
} while (0)

#define LDB(BS, BF) do {                                                       \
    _Pragma("unroll")                                                          \
    for (int j_ = 0; j_ < 2; j_++)                                             \
    _Pragma("unroll")                                                          \
    for (int kh_ = 0; kh_ < 2; kh_++) {                                        \
        int row_ = wn * 32 + j_ * 16 + (lane & 15);                            \
        int cc_ = kh_ * 4 + (lane >> 4);                                       \
        BF[j_][kh_] = *(const bf16x8*)&(BS)[row_ * BK + ((cc_ ^ (row_ & 7)) << 3)]; \
    }                                                                          \
} while (0)

#define MM(ACC, H, BF) do {                                                    \
    __builtin_amdgcn_s_setprio(1);                                             \
    _Pragma("unroll")                                                          \
    for (int i_ = 0; i_ < 4; i_++)                                             \
    _Pragma("unroll")                                                          \
    for (int j_ = 0; j_ < 2; j_++)                                             \
    _Pragma("unroll")                                                          \
    for (int kh_ = 0; kh_ < 2; kh_++)                                          \
        ACC[(H) * 4 + i_][j_] = __builtin_amdgcn_mfma_f32_16x16x32_bf16(       \
            af[i_][kh_], BF[j_][kh_], ACC[(H) * 4 + i_][j_], 0, 0, 0);         \
    __builtin_amdgcn_s_setprio(0);                                             \
} while (0)

#define FENCE() asm volatile("" ::: "memory")
#define BARRIER() do { FENCE(); __builtin_amdgcn_s_barrier(); FENCE(); } while (0)

__global__ __launch_bounds__(512, 2) void gemm_fused(
    const ushort* __restrict__ xb, const ushort* __restrict__ wb,
    const ushort* __restrict__ rb,
    const float* __restrict__ mb2, const float* __restrict__ rb2,
    float* __restrict__ out) {
    __shared__ ushort As[2][BM * BK];    // 2 x 32 KB
    __shared__ ushort B1s[2][BN * BK];   // 2 x 16 KB
    __shared__ ushort B2s[2][BN * BK];   // 2 x 16 KB

    int tid   = threadIdx.x;
    int lane  = tid & 63;
    int wid   = tid >> 6;        // 0..7
    int wm    = wid >> 2;        // 0..1 -> 128-row half
    int wn    = wid & 3;         // 0..3 -> 32-col quarter
    int wbase = tid & ~63;

    // T1: bijective XCD swizzle (2048 % 8 == 0)
    int wg = blockIdx.x;
    int wgs = (wg & 7) * 256 + (wg >> 3);
    int tile_m = wgs >> 6;       // 0..31
    int tile_n = wgs & 63;       // 0..63
    int brow = tile_m * BM;
    int bn0  = tile_n * BN;

    const ushort* xg  = xb + (size_t)brow * DDIM;
    const ushort* w1g = wb + (size_t)bn0 * DDIM;
    const ushort* w2g = rb + (size_t)bn0 * DDIM;

    f32x4 acc1[8][2] = {};
    f32x4 acc2[8][2] = {};
    bf16x8 af[4][2], bf1[2][2], bf2[2][2];

    // prologue: stage step 0 (units U0=A-half0, U1=A-half1, U2=B1, U3=B2)
    STAGE(xg,              As[0]);
    STAGE(xg + 128 * DDIM, As[0] + 128 * BK);
    STAGE(w1g,             B1s[0]);
    STAGE(w2g,             B2s[0]);
    asm volatile("s_waitcnt vmcnt(2)" ::: "memory");   // U0..U2 done, U3 in flight
    BARRIER();

#pragma unroll 2
    for (int t = 0; t < NT; ++t) {
        int buf = t & 1;
        ushort* Ac  = As[buf];
        ushort* B1c = B1s[buf];
        ushort* B2c = B2s[buf];
        ushort* An  = As[buf ^ 1];
        ushort* B1n = B1s[buf ^ 1];
        ushort* B2n = B2s[buf ^ 1];
        const int kn = (t + 1) * BK;
        const bool stage = (t + 1 < NT);

        // ---- phase 0: A-h0 + B1 reads | stage U0(t+1) | MFMA acc1 h0 ----
        LDA(Ac, 0);
        LDB(B1c, bf1);
        if (stage) STAGE(xg + kn, An);
        BARRIER();
        MM(acc1, 0, bf1);
        if (stage) asm volatile("s_waitcnt vmcnt(2)" ::: "memory");  // U3(t) done
        else       asm volatile("s_waitcnt vmcnt(0)" ::: "memory");
        BARRIER();

        // ---- phase 1: B2 reads | stage U1(t+1) | MFMA acc2 h0 ----
        LDB(B2c, bf2);
        if (stage) STAGE(xg + 128 * DDIM + kn, An + 128 * BK);
        BARRIER();
        MM(acc2, 0, bf2);
        BARRIER();

        // ---- phase 2: A-h1 reads | stage U2(t+1) | MFMA acc1 h1 ----
        LDA(Ac, 1);
        if (stage) STAGE(w1g + kn, B1n);
        BARRIER();
        MM(acc1, 1, bf1);
        BARRIER();

        // ---- phase 3: (frags held) | stage U3(t+1) | MFMA acc2 h1 ----
        if (stage) STAGE(w2g + kn, B2n);
        BARRIER();
        MM(acc2, 1, bf2);
        if (stage) asm volatile("s_waitcnt vmcnt(2)" ::: "memory");  // U0..U2(t+1) done
        BARRIER();
    }

    // ---- epilogue: p = (acc1+b1)(acc2+b2); reduce over m (8 adjacent n');
    // n' = c*8 + m -> 3x shfl_xor; plain stores, disjoint per block ----
#pragma unroll
    for (int j = 0; j < 2; j++) {
        int np = bn0 + wn * 32 + j * 16 + (lane & 15);
        float bb1 = mb2[np];
        float bb2 = rb2[np];
        int c = tile_n * 16 + wn * 4 + j * 2 + ((lane >> 3) & 1);
#pragma unroll
        for (int rf = 0; rf < 8; rf++) {
#pragma unroll
            for (int r = 0; r < 4; r++) {
                float p = (acc1[rf][j][r] + bb1) * (acc2[rf][j][r] + bb2);
                p += __shfl_xor(p, 1);
                p += __shfl_xor(p, 2);
                p += __shfl_xor(p, 4);
                if ((lane & 7) == 0 && c < CDIM) {
                    int row = brow + wm * 128 + rf * 16 + ((lane >> 4) << 2) + r;
                    out[(size_t)row * CDIM + c] = p;
                }
            }
        }
    }
}

extern "C" void kernel_launch(void* const* d_in, const int* in_sizes, int n_in,
                              void* d_out, int out_size, void* d_ws, size_t ws_size,
                              hipStream_t stream) {
    const float* x   = (const float*)d_in[0];   // [8192][2048]
    const float* mw  = (const float*)d_in[1];   // [8][2048][1000]
    const float* mb  = (const float*)d_in[2];   // [8][1000]
    const float* rw  = (const float*)d_in[3];   // [2048][8000]
    const float* rbv = (const float*)d_in[4];   // [8000]
    float* out = (float*)d_out;                 // [8192][1000]

    char* ws = (char*)d_ws;
    ushort* xb  = (ushort*)ws;                                  // 33,554,432 B
    ushort* wb  = (ushort*)(ws + (size_t)33554432);             // 33,554,432 B
    ushort* rb  = (ushort*)(ws + (size_t)67108864);             // 33,554,432 B
    float*  mb2 = (float*)(ws + (size_t)100663296);             // 32,768 B
    float*  rb2 = (float*)(ws + (size_t)100696064);             // 32,768 B

    cast_x_kernel<<<BDIM * DDIM / (256 * 4), 256, 0, stream>>>((const float4*)x, xb);
    prep_w<<<dim3(CPAD / 32, DDIM / 32, MDIM), dim3(32, 8), 0, stream>>>(mw, wb);
    prep_r<<<dim3(CPAD / 32, DDIM / 32, MDIM), dim3(32, 8), 0, stream>>>(rw, rb);
    prep_bias<<<NPAD / 256, 256, 0, stream>>>(mb, rbv, mb2, rb2);

    gemm_fused<<<dim3((BDIM / BM) * (NPAD / BN)), 512, 0, stream>>>(xb, wb, rb, mb2, rb2, out);
}

// Round 4
// 578.155 us; speedup vs baseline: 1.3595x; 1.0474x over previous
//
#include <hip/hip_runtime.h>
#include <hip/hip_bf16.h>
#include <stdint.h>

// B=8192, D=2048, M=8, C=1000; padded: CPAD=1024, NPAD=8192 (n' = c*8 + m)
#define BDIM 8192
#define DDIM 2048
#define MDIM 8
#define CDIM 1000
#define CPAD 1024
#define NPAD 8192

typedef __attribute__((ext_vector_type(8))) short bf16x8;
typedef __attribute__((ext_vector_type(4))) float f32x4;

__device__ __forceinline__ unsigned short f2bf(float f) {
    union { float f; unsigned u; } v; v.f = f;
    unsigned r = v.u + 0x7fffu + ((v.u >> 16) & 1u);   // RNE
    return (unsigned short)(r >> 16);
}

__device__ __forceinline__ void gl_lds16(const void* g, void* l) {
    __builtin_amdgcn_global_load_lds(
        (const __attribute__((address_space(1))) void*)g,
        (__attribute__((address_space(3))) void*)l,
        16, 0, 0);
}

// ---------------- prep: cast x (fp32 -> bf16) ----------------
__global__ void cast_x_kernel(const float4* __restrict__ x, ushort* __restrict__ xb) {
    int i = blockIdx.x * blockDim.x + threadIdx.x;
    float4 v = x[i];
    ushort4 o;
    o.x = f2bf(v.x); o.y = f2bf(v.y); o.z = f2bf(v.z); o.w = f2bf(v.w);
    *(ushort4*)&xb[(size_t)i * 4] = o;
}

// ---- prep: model_weights (M,D,C) -> wb[n'=c*8+m][d], zero-pad c>=1000 ----
__global__ void prep_w(const float* __restrict__ MW, ushort* __restrict__ wb) {
    __shared__ float tile[32][33];
    int m  = blockIdx.z;
    int c0 = blockIdx.x * 32;
    int d0 = blockIdx.y * 32;
    int tx = threadIdx.x, ty = threadIdx.y;
    const float* src = MW + (size_t)m * DDIM * CDIM;
#pragma unroll
    for (int i = 0; i < 4; i++) {
        int d = d0 + ty + i * 8;
        int c = c0 + tx;
        tile[ty + i * 8][tx] = (c < CDIM) ? src[(size_t)d * CDIM + c] : 0.f;
    }
    __syncthreads();
#pragma unroll
    for (int i = 0; i < 4; i++) {
        int c = c0 + ty + i * 8;
        int d = d0 + tx;
        wb[(size_t)(c * 8 + m) * DDIM + d] = f2bf(tile[tx][ty + i * 8]);
    }
}

// ---- prep: resnet_weight (D, 8000) -> rb[n'=c*8+m][d], zero-pad c>=1000 ----
__global__ void prep_r(const float* __restrict__ R, ushort* __restrict__ rb) {
    __shared__ float tile[32][33];
    int m  = blockIdx.z;
    int c0 = blockIdx.x * 32;
    int d0 = blockIdx.y * 32;
    int tx = threadIdx.x, ty = threadIdx.y;
#pragma unroll
    for (int i = 0; i < 4; i++) {
        int d = d0 + ty + i * 8;
        int c = c0 + tx;
        tile[ty + i * 8][tx] = (c < CDIM) ? R[(size_t)d * (MDIM * CDIM) + m * CDIM + c] : 0.f;
    }
    __syncthreads();
#pragma unroll
    for (int i = 0; i < 4; i++) {
        int c = c0 + ty + i * 8;
        int d = d0 + tx;
        rb[(size_t)(c * 8 + m) * DDIM + d] = f2bf(tile[tx][ty + i * 8]);
    }
}

// ---- prep: biases -> interleaved padded float arrays [NPAD] ----
__global__ void prep_bias(const float* __restrict__ mb, const float* __restrict__ rbv,
                          float* __restrict__ mb2, float* __restrict__ rb2) {
    int n = blockIdx.x * 256 + threadIdx.x;   // 0..8191
    int c = n >> 3, m = n & 7;
    mb2[n] = (c < CDIM) ? mb[m * CDIM + c] : 0.f;
    rb2[n] = (c < CDIM) ? rbv[m * CDIM + c] : 0.f;
}

// ---------------- fused dual-B GEMM, 4-phase pipelined ----------------
#define BM 256
#define BN 128
#define BK 64
#define NT (DDIM / BK)   // 32

// stage one 16KB unit (128 rows x 64 ushorts), inverse-swizzled global source,
// linear LDS dest (wave-uniform base + lane*16). 2 gl_lds insts per thread.
#define STAGE(G, L) do {                                                       \
    _Pragma("unroll")                                                          \
    for (int it_ = 0; it_ < 2; ++it_) {                                        \
        int ci_ = it_ * 512 + tid;                                             \
        int r_ = ci_ >> 3, cc_ = ci_ & 7;                                      \
        gl_lds16((G) + (size_t)r_ * DDIM + (size_t)((cc_ ^ (r_ & 7)) << 3),    \
                 (L) + (size_t)(it_ * 512 + wbase) * 8);                       \
    }                                                                          \
} while (0)

// H selects a CONTIGUOUS 128-row half (matches the staged unit: U0 = rows
// 0..127, U3 = rows 128..255); wm picks the 64-row half within the unit.
#define LDA(AC, H) do {                                                        \
    _Pragma("unroll")                                                          \
    for (int i_ = 0; i_ < 4; i_++)                                             \
    _Pragma("unroll")                                                          \
    for (int kh_ = 0; kh_ < 2; kh_++) {                                        \
        int row_ = (H) * 128 + wm * 64 + i_ * 16 + (lane & 15);                \
        int cc_ = kh_ * 4 + (lane >> 4);                                       \
        af[i_][kh_] = *(const bf16x8*)&(AC)[row_ * BK + ((cc_ ^ (row_ & 7)) << 3)]; \
    }                                                                          \
} while (0)

#define LDB(BS, BF) do {                                                       \
    _Pragma("unroll")                                                          \
    for (int j_ = 0; j_ < 2; j_++)                                             \
    _Pragma("unroll")                                                          \
    for (int kh_ = 0; kh_ < 2; kh_++) {                                        \
        int row_ = wn * 32 + j_ * 16 + (lane & 15);                            \
        int cc_ = kh_ * 4 + (lane >> 4);                                       \
        BF[j_][kh_] = *(const bf16x8*)&(BS)[row_ * BK + ((cc_ ^ (row_ & 7)) << 3)]; \
    }                                                                          \
} while (0)

#define MM(ACC, H, BF) do {                                                    \
    __builtin_amdgcn_s_setprio(1);                                             \
    _Pragma("unroll")                                                          \
    for (int i_ = 0; i_ < 4; i_++)                                             \
    _Pragma("unroll")                                                          \
    for (int j_ = 0; j_ < 2; j_++)                                             \
    _Pragma("unroll")                                                          \
    for (int kh_ = 0; kh_ < 2; kh_++)                                          \
        ACC[(H) * 4 + i_][j_] = __builtin_amdgcn_mfma_f32_16x16x32_bf16(       \
            af[i_][kh_], BF[j_][kh_], ACC[(H) * 4 + i_][j_], 0, 0, 0);         \
    __builtin_amdgcn_s_setprio(0);                                             \
} while (0)

#define FENCE() asm volatile("" ::: "memory")
#define BARRIER() do { FENCE(); __builtin_amdgcn_s_barrier(); FENCE(); } while (0)
#define WAITV(N) asm volatile("s_waitcnt vmcnt(" #N ")" ::: "memory")

__global__ __launch_bounds__(512, 2) void gemm_fused(
    const ushort* __restrict__ xb, const ushort* __restrict__ wb,
    const ushort* __restrict__ rb,
    const float* __restrict__ mb2, const float* __restrict__ rb2,
    float* __restrict__ out) {
    __shared__ ushort As[2][BM * BK];    // 2 x 32 KB
    __shared__ ushort B1s[2][BN * BK];   // 2 x 16 KB
    __shared__ ushort B2s[2][BN * BK];   // 2 x 16 KB

    int tid   = threadIdx.x;
    int lane  = tid & 63;
    int wid   = tid >> 6;        // 0..7
    int wm    = wid >> 2;        // 0..1 -> 64-row half within each A unit
    int wn    = wid & 3;         // 0..3 -> 32-col quarter
    int wbase = tid & ~63;

    // T1: bijective XCD swizzle (2048 % 8 == 0)
    int wg = blockIdx.x;
    int wgs = (wg & 7) * 256 + (wg >> 3);
    int tile_m = wgs >> 6;       // 0..31
    int tile_n = wgs & 63;       // 0..63
    int brow = tile_m * BM;
    int bn0  = tile_n * BN;

    const ushort* xg  = xb + (size_t)brow * DDIM;
    const ushort* w1g = wb + (size_t)bn0 * DDIM;
    const ushort* w2g = rb + (size_t)bn0 * DDIM;

    f32x4 acc1[8][2] = {};
    f32x4 acc2[8][2] = {};
    bf16x8 af[4][2], bf1[2][2], bf2[2][2];

    // prologue: stage tile 0 in CONSUMPTION order:
    // U0 = A rows 0..127 (ph0), U1 = B1 (ph0), U2 = B2 (ph1), U3 = A rows 128..255 (ph2)
    STAGE(xg,              As[0]);
    STAGE(w1g,             B1s[0]);
    STAGE(w2g,             B2s[0]);
    STAGE(xg + 128 * DDIM, As[0] + 128 * BK);
    WAITV(4);                 // U0,U1 done; U2,U3 in flight
    BARRIER();

    // steady state: always stage tile t+1, unit issue order matches consumption
#pragma unroll 2
    for (int t = 0; t < NT - 1; ++t) {
        int buf = t & 1;
        ushort* Ac  = As[buf];
        ushort* B1c = B1s[buf];
        ushort* B2c = B2s[buf];
        ushort* An  = As[buf ^ 1];
        ushort* B1n = B1s[buf ^ 1];
        ushort* B2n = B2s[buf ^ 1];
        const int kn = (t + 1) * BK;

        // ph0: reads A rows 0..127 + B1 | stage U0(t+1) | MFMA acc1 h0
        LDA(Ac, 0);
        LDB(B1c, bf1);
        STAGE(xg + kn, An);
        BARRIER();
        MM(acc1, 0, bf1);
        WAITV(4);            // drains B2(t)   [next phase reads it]
        BARRIER();

        // ph1: reads B2 | stage U1(t+1)=B1 | MFMA acc2 h0
        LDB(B2c, bf2);
        STAGE(w1g + kn, B1n);
        BARRIER();
        MM(acc2, 0, bf2);
        WAITV(4);            // drains A rows 128..255 (t) [next phase reads it]
        BARRIER();

        // ph2: reads A rows 128..255 | stage U2(t+1)=B2 | MFMA acc1 h1
        LDA(Ac, 1);
        STAGE(w2g + kn, B2n);
        BARRIER();
        MM(acc1, 1, bf1);
        BARRIER();

        // ph3: (frags held) | stage U3(t+1) | MFMA acc2 h1
        STAGE(xg + 128 * DDIM + kn, An + 128 * BK);
        BARRIER();
        MM(acc2, 1, bf2);
        WAITV(4);            // drains U0(t+1), B1(t+1) [ph0 of t+1 reads them]
        BARRIER();
    }

    // peeled final K-step (t = NT-1): no staging, tight drains
    {
        ushort* Ac  = As[(NT - 1) & 1];
        ushort* B1c = B1s[(NT - 1) & 1];
        ushort* B2c = B2s[(NT - 1) & 1];

        LDA(Ac, 0);
        LDB(B1c, bf1);
        BARRIER();
        MM(acc1, 0, bf1);
        WAITV(2);            // drains B2
        BARRIER();

        LDB(B2c, bf2);
        BARRIER();
        MM(acc2, 0, bf2);
        WAITV(0);            // drains A rows 128..255
        BARRIER();

        LDA(Ac, 1);
        BARRIER();
        MM(acc1, 1, bf1);
        MM(acc2, 1, bf2);
    }

    // ---- epilogue: p = (acc1+b1)(acc2+b2); reduce over m (8 adjacent n');
    // n' = c*8 + m -> 3x shfl_xor; plain stores, disjoint per block.
    // acc rf = H*4+i -> tile row = (rf>>2)*128 + wm*64 + (rf&3)*16 + frag row ----
#pragma unroll
    for (int j = 0; j < 2; j++) {
        int np = bn0 + wn * 32 + j * 16 + (lane & 15);
        float bb1 = mb2[np];
        float bb2 = rb2[np];
        int c = tile_n * 16 + wn * 4 + j * 2 + ((lane >> 3) & 1);
#pragma unroll
        for (int rf = 0; rf < 8; rf++) {
#pragma unroll
            for (int r = 0; r < 4; r++) {
                float p = (acc1[rf][j][r] + bb1) * (acc2[rf][j][r] + bb2);
                p += __shfl_xor(p, 1);
                p += __shfl_xor(p, 2);
                p += __shfl_xor(p, 4);
                if ((lane & 7) == 0 && c < CDIM) {
                    int row = brow + (rf >> 2) * 128 + wm * 64 + (rf & 3) * 16
                              + ((lane >> 4) << 2) + r;
                    out[(size_t)row * CDIM + c] = p;
                }
            }
        }
    }
}

extern "C" void kernel_launch(void* const* d_in, const int* in_sizes, int n_in,
                              void* d_out, int out_size, void* d_ws, size_t ws_size,
                              hipStream_t stream) {
    const float* x   = (const float*)d_in[0];   // [8192][2048]
    const float* mw  = (const float*)d_in[1];   // [8][2048][1000]
    const float* mb  = (const float*)d_in[2];   // [8][1000]
    const float* rw  = (const float*)d_in[3];   // [2048][8000]
    const float* rbv = (const float*)d_in[4];   // [8000]
    float* out = (float*)d_out;                 // [8192][1000]

    char* ws = (char*)d_ws;
    ushort* xb  = (ushort*)ws;                                  // 33,554,432 B
    ushort* wb  = (ushort*)(ws + (size_t)33554432);             // 33,554,432 B
    ushort* rb  = (ushort*)(ws + (size_t)67108864);             // 33,554,432 B
    float*  mb2 = (float*)(ws + (size_t)100663296);             // 32,768 B
    float*  rb2 = (float*)(ws + (size_t)100696064);             // 32,768 B

    cast_x_kernel<<<BDIM * DDIM / (256 * 4), 256, 0, stream>>>((const float4*)x, xb);
    prep_w<<<dim3(CPAD / 32, DDIM / 32, MDIM), dim3(32, 8), 0, stream>>>(mw, wb);
    prep_r<<<dim3(CPAD / 32, DDIM / 32, MDIM), dim3(32, 8), 0, stream>>>(rw, rb);
    prep_bias<<<NPAD / 256, 256, 0, stream>>>(mb, rbv, mb2, rb2);

    gemm_fused<<<dim3((BDIM / BM) * (NPAD / BN)), 512, 0, stream>>>(xb, wb, rb, mb2, rb2, out);
}